// Round 6
// baseline (931.034 us; speedup 1.0000x reference)
//
#include <hip/hip_runtime.h>
#include <hip/hip_bf16.h>

// Chronos2Attention on MI355X (gfx950). Inputs f32, output f32.
// Internally bf16 MFMA with fp32 accumulation.
// B=4, S=2048, D=1024, H=16, Dh=64. RoPE theta=10000, no 1/sqrt(d) scale.
//
// R6: attention restructured kv-split (R5 was LDS-pipe-bound at ~122 µs DS
// model: 4 waves each read full K+V tiles = 4x amplification). Now KV
// tile=128, wave w owns kv slice w*32..+31 for ALL 64 q rows: K/V frag
// reads cut 4x; partial-O per wave reduced once at end via phased LDS.
// GEMM/aux kernels identical to R5 (passed, absmax 0.0098).
//
// Workspace (72 MB):
//   0..6MB WtQKV | 6..8MB WtO | 8..24MB hsb->VT | 24..40 Qw | 40..56 Kw
//   56..72MB Vw->Ow

typedef __bf16 bf16_t;
typedef __bf16 bf16x4 __attribute__((ext_vector_type(4)));
typedef __bf16 bf16x8 __attribute__((ext_vector_type(8)));
typedef float f32x4 __attribute__((ext_vector_type(4)));

#define MFMA16(a, b, c) __builtin_amdgcn_mfma_f32_16x16x32_bf16((a), (b), (c), 0, 0, 0)

#define GLOAD_LDS(gp, lp) \
  __builtin_amdgcn_global_load_lds( \
      (const __attribute__((address_space(1))) void*)(gp), \
      (__attribute__((address_space(3))) void*)(lp), 16, 0, 0)

// ---------------------------------------------------------------- hs f32->bf16
__global__ __launch_bounds__(256) void cvt_kernel(const float* __restrict__ X,
                                                  bf16_t* __restrict__ Y) {
  const int i = (blockIdx.x * 256 + threadIdx.x) * 4;
  const f32x4 x = *(const f32x4*)(X + i);
  bf16x4 y;
#pragma unroll
  for (int k = 0; k < 4; k++) y[k] = (bf16_t)x[k];
  *(bf16x4*)(Y + i) = y;
}

// ---------------------------------------------------------------- weight transpose
__global__ __launch_bounds__(256) void wtrans4_kernel(
    const float* __restrict__ w0, const float* __restrict__ w1,
    const float* __restrict__ w2, const float* __restrict__ w3,
    bf16_t* __restrict__ out) {
  __shared__ bf16_t t[32][33];
  const int tx = threadIdx.x, ty = threadIdx.y;
  const int bx = blockIdx.x, by = blockIdx.y, z = blockIdx.z;
  const float* W = (z == 0) ? w0 : (z == 1) ? w1 : (z == 2) ? w2 : w3;
  bf16_t* Wt = out + (size_t)z * 1024 * 1024;
#pragma unroll
  for (int i = ty; i < 32; i += 8)
    t[i][tx] = (bf16_t)W[(size_t)(by * 32 + i) * 1024 + bx * 32 + tx];
  __syncthreads();
#pragma unroll
  for (int i = ty; i < 32; i += 8)
    Wt[(size_t)(bx * 32 + i) * 1024 + by * 32 + tx] = t[tx][i];
}

// ---------------------------------------------------------------- V transpose
// VT[b*1024 + c][s] = Vw[b*2048 + s][c].
__global__ __launch_bounds__(256) void vtrans_kernel(const bf16_t* __restrict__ V,
                                                     bf16_t* __restrict__ VT) {
  __shared__ bf16_t t[32][33];
  const int tx = threadIdx.x, ty = threadIdx.y;
  const int sx = blockIdx.x * 32, cy = blockIdx.y * 32, b = blockIdx.z;
  const bf16_t* Vb = V + (size_t)b * 2048 * 1024;
  bf16_t* VTb = VT + (size_t)b * 1024 * 2048;
#pragma unroll
  for (int i = ty; i < 32; i += 8)
    t[i][tx] = Vb[(size_t)(sx + i) * 1024 + cy + tx];
  __syncthreads();
#pragma unroll
  for (int i = ty; i < 32; i += 8)
    VTb[(size_t)(cy + i) * 2048 + sx + tx] = t[tx][i];
}

// ---------------------------------------------------------------- GEMM (+RoPE)
// Identical to R5 (proven): 128x128 tile, global_load_lds w=16, XOR swizzle.
template <typename TC, bool FUSED_QKV>
__global__ __launch_bounds__(256) void gemm_kernel(
    const bf16_t* __restrict__ A, const bf16_t* __restrict__ BtBase,
    TC* __restrict__ CBase, const int ropeIn) {
  constexpr int K = 1024, N = 1024;
  __shared__ __align__(16) bf16_t As[128 * 32];
  __shared__ __align__(16) bf16_t Bs[128 * 32];

  const int tid = threadIdx.x;
  const int lane = tid & 63, w = tid >> 6;
  const int l15 = lane & 15, quad = lane >> 4;
  const int wm = w >> 1, wn = w & 1;
  const int m0 = blockIdx.x * 128;

  int n0, rope;
  const bf16_t* Bt;
  TC* C;
  if (FUSED_QKV) {
    const int which = blockIdx.y >> 3;
    n0 = (blockIdx.y & 7) * 128;
    Bt = BtBase + (size_t)which * (1u << 20);
    C = CBase + (size_t)which * (8u << 20);
    rope = (which < 2);
  } else {
    n0 = blockIdx.y * 128;
    Bt = BtBase;
    C = CBase;
    rope = ropeIn;
  }

  f32x4 acc[4][4] = {};
  const int li8 = lane >> 3, j = lane & 7;

  for (int k0 = 0; k0 < K; k0 += 32) {
#pragma unroll
    for (int p = 0; p < 2; ++p) {
      const int g = w * 16 + p * 8 + li8;
      const int jp = j ^ (g & 7);
      const int row = 2 * g + (jp >> 2), kb = jp & 3;
      GLOAD_LDS(A + (size_t)(m0 + row) * K + k0 + kb * 8, As + (w * 16 + p * 8) * 64);
      GLOAD_LDS(Bt + (size_t)(n0 + row) * K + k0 + kb * 8, Bs + (w * 16 + p * 8) * 64);
    }
    __syncthreads();

    bf16x8 af[4], bfv[4];
#pragma unroll
    for (int mi = 0; mi < 4; mi++) {
      const int R = wm * 64 + mi * 16 + l15, g = R >> 1;
      const int jj = (((R & 1) << 2) | quad) ^ (g & 7);
      af[mi] = *(const bf16x8*)(As + g * 64 + jj * 8);
    }
#pragma unroll
    for (int ni = 0; ni < 4; ni++) {
      const int R = wn * 64 + ni * 16 + l15, g = R >> 1;
      const int jj = (((R & 1) << 2) | quad) ^ (g & 7);
      bfv[ni] = *(const bf16x8*)(Bs + g * 64 + jj * 8);
    }
#pragma unroll
    for (int mi = 0; mi < 4; mi++)
#pragma unroll
      for (int ni = 0; ni < 4; ni++)
        acc[mi][ni] = MFMA16(af[mi], bfv[ni], acc[mi][ni]);
    __syncthreads();
  }

#pragma unroll
  for (int mi = 0; mi < 4; mi++) {
    const int rbase = m0 + wm * 64 + mi * 16 + quad * 4;
    if (rope) {
#pragma unroll
      for (int r = 0; r < 4; r++) {
        const float pos = (float)((rbase + r) & 2047);
#pragma unroll
        for (int ni = 0; ni < 2; ni++) {
          const int d2 = ni * 16 + l15;
          const float invf = __powf(10000.0f, -(float)d2 * (1.0f / 32.0f));
          float sv, cv;
          __sincosf(pos * invf, &sv, &cv);
          const float a0 = acc[mi][ni][r], a2 = acc[mi][ni + 2][r];
          acc[mi][ni][r] = a0 * cv - a2 * sv;
          acc[mi][ni + 2][r] = a2 * cv + a0 * sv;
        }
      }
    }
#pragma unroll
    for (int ni = 0; ni < 4; ni++) {
      const int c0 = n0 + wn * 64 + ni * 16 + l15;
#pragma unroll
      for (int r = 0; r < 4; r++)
        C[(size_t)(rbase + r) * N + c0] = (TC)acc[mi][ni][r];
    }
  }
}

// ---------------------------------------------------------------- attention (R6)
// Block = 64 q rows of one (b,h), 4 waves, KV tile 128, wave w owns kv
// slice w*32..+31 for ALL 64 q. Q held in regs (8 A-frags). Per wave:
// QK = 16 MFMAs over its slice (4 K-frag b128 reads), exp -> per-wave P
// [64 q][32 kv] in LDS (m120 C->A transform), PV = 16 MFMAs with k=32
// (4 P-rd + 4 V-rd b128) into partial O[64][64]. End: phased cross-wave
// O + lsum reduction in LDS (reusing the K/V/P arena), coalesced store.
#define PLSTR 40  // 32 kv + 8 pad (80 B rows: 16B-aligned for b128 reads)

__global__ __launch_bounds__(256, 2) void attn_kernel(const bf16_t* __restrict__ Q,
                                                      const bf16_t* __restrict__ K,
                                                      const bf16_t* __restrict__ VT,
                                                      bf16_t* __restrict__ O) {
  __shared__ __align__(16) char arena[53248];
  bf16_t* Kl = (bf16_t*)arena;             // [kv 128][d 64], XOR-swizzled, 16 KB
  bf16_t* Vl = (bf16_t*)(arena + 16384);   // [g=d*2+h][64], XOR-swizzled, 16 KB
  bf16_t* Pl = (bf16_t*)(arena + 32768);   // per-wave [64 q][PLSTR], 20 KB
  float* Obuf = (float*)arena;             // [64][68] f32 (after loop), 17.4 KB
  float* lsumB = (float*)(arena + 32768);  // [4][64] (after loop, in Pl region)

  const int tid = threadIdx.x;
  const int lane = tid & 63, w = tid >> 6;
  const int l15 = lane & 15, quad = lane >> 4;
  const int li8 = lane >> 3, j = lane & 7;
  const int q0 = blockIdx.x * 64;
  const int bh = blockIdx.y, b = bh >> 4, h = bh & 15;

  const size_t base = (size_t)b * 2048 * 1024 + (size_t)h * 64;
  const bf16_t* Qb = Q + base;
  const bf16_t* Kb = K + base;
  const bf16_t* VTb = VT + (size_t)(b * 1024 + h * 64) * 2048;

  // Q A-frags: qf[mb][t]: A[m = q0+mb*16+l15][k = t*32+quad*8 ..+7]
  bf16x8 qf[4][2];
#pragma unroll
  for (int mb = 0; mb < 4; mb++)
#pragma unroll
    for (int t = 0; t < 2; t++)
      qf[mb][t] = *(const bf16x8*)(Qb + (size_t)(q0 + mb * 16 + l15) * 1024 + t * 32 + quad * 8);

  f32x4 accO[4][4] = {};          // partial O[q mb][d nb] over this wave's kv
  float lsum[4][4] = {};          // partial row sums [mb][r]
  bf16_t* Plw = Pl + w * (64 * PLSTR);

  for (int kv0 = 0; kv0 < 2048; kv0 += 128) {
    // stage K[128][64] and V^T[64][128] tiles; group = 128B row-chunk;
    // slot j holds chunk j^(g&7) (2-way reads = free, m136)
#pragma unroll
    for (int p = 0; p < 4; ++p) {
      const int g = w * 32 + p * 8 + li8;
      const int blk = j ^ (g & 7);
      GLOAD_LDS(Kb + (size_t)(kv0 + g) * 1024 + blk * 8, Kl + (w * 32 + p * 8) * 64);
      GLOAD_LDS(VTb + (size_t)(g >> 1) * 2048 + kv0 + (g & 1) * 64 + blk * 8,
                Vl + (w * 32 + p * 8) * 64);
    }
    __syncthreads();

    // S slice = Q K^T : wave w computes S[64 q][kv w*32 .. +31]
#pragma unroll
    for (int nb2 = 0; nb2 < 2; nb2++) {
      f32x4 sc[4] = {};
#pragma unroll
      for (int t = 0; t < 2; t++) {
        const int R = w * 32 + nb2 * 16 + l15;  // kv row (= group)
        const int jj = (t * 4 + quad) ^ (R & 7);
        const bf16x8 kf = *(const bf16x8*)(Kl + R * 64 + jj * 8);
#pragma unroll
        for (int mb = 0; mb < 4; mb++)
          sc[mb] = MFMA16(qf[mb][t], kf, sc[mb]);
      }
      // exp + partial sums + P store (C-layout -> slice-local [q][kv32])
#pragma unroll
      for (int mb = 0; mb < 4; mb++)
#pragma unroll
        for (int r = 0; r < 4; r++) {
          const float p = __expf(sc[mb][r]);
          lsum[mb][r] += p;
          Plw[(mb * 16 + quad * 4 + r) * PLSTR + nb2 * 16 + l15] = (bf16_t)p;
        }
    }
    __asm__ volatile("s_waitcnt lgkmcnt(0)" ::: "memory");  // per-wave Pl drain

    // O_partial += P V over kv slice (k=32 exactly):
    // A-frag pf[mb]: P[q mb*16+l15][kv quad*8+j]; B-frag vf[nb]: V[kv][d nb*16+l15]
    bf16x8 pf[4], vf[4];
#pragma unroll
    for (int mb = 0; mb < 4; mb++)
      pf[mb] = *(const bf16x8*)(Plw + (mb * 16 + l15) * PLSTR + quad * 8);
#pragma unroll
    for (int nb = 0; nb < 4; nb++) {
      const int R = nb * 16 + l15;           // d row
      const int g = R * 2 + (w >> 1);        // VT group: half = w>>1
      const int jj = ((w & 1) * 4 + quad) ^ (g & 7);  // chunk = kv-in-half/8
      vf[nb] = *(const bf16x8*)(Vl + g * 64 + jj * 8);
    }
#pragma unroll
    for (int mb = 0; mb < 4; mb++)
#pragma unroll
      for (int nb = 0; nb < 4; nb++)
        accO[mb][nb] = MFMA16(pf[mb], vf[nb], accO[mb][nb]);
    __syncthreads();  // Kl/Vl reuse next tile
  }

  // ---- cross-wave reduction (arena reused; all waves past final barrier) ----
  // lsum: reduce over this wave's 16 kv-lanes, publish per-wave partials
#pragma unroll
  for (int mb = 0; mb < 4; mb++)
#pragma unroll
    for (int r = 0; r < 4; r++) {
      float s = lsum[mb][r];
      s += __shfl_xor(s, 1);
      s += __shfl_xor(s, 2);
      s += __shfl_xor(s, 4);
      s += __shfl_xor(s, 8);
      lsum[mb][r] = s;
    }
  if (l15 == 0) {
#pragma unroll
    for (int mb = 0; mb < 4; mb++)
#pragma unroll
      for (int r = 0; r < 4; r++)
        lsumB[w * 64 + mb * 16 + quad * 4 + r] = lsum[mb][r];
  }

  // O: phased accumulation into Obuf[64][68] (each phase: 4 waves hit 4
  // distinct 16-row blocks; C-layout row = quad*4+r, col = nb*16+l15)
#pragma unroll
  for (int p = 0; p < 4; p++) {
    const int s = (w + p) & 3;
    if (p == 0) {
#pragma unroll
      for (int nb = 0; nb < 4; nb++)
#pragma unroll
        for (int r = 0; r < 4; r++)
          Obuf[(s * 16 + quad * 4 + r) * 68 + nb * 16 + l15] = accO[s][nb][r];
    } else {
#pragma unroll
      for (int nb = 0; nb < 4; nb++)
#pragma unroll
        for (int r = 0; r < 4; r++)
          Obuf[(s * 16 + quad * 4 + r) * 68 + nb * 16 + l15] += accO[s][nb][r];
    }
    __syncthreads();
  }

  // final: wave w stores q rows w*16..+15, coalesced bf16x4
  bf16_t* Ob = O + base;
#pragma unroll
  for (int rr = 0; rr < 4; rr++) {
    const int row = w * 16 + rr * 4 + quad;
    const f32x4 o = *(const f32x4*)(Obuf + row * 68 + l15 * 4);
    const float inv =
        1.0f / (lsumB[row] + lsumB[64 + row] + lsumB[128 + row] + lsumB[192 + row]);
    bf16x4 ob;
#pragma unroll
    for (int c = 0; c < 4; c++) ob[c] = (bf16_t)(o[c] * inv);
    *(bf16x4*)(Ob + (size_t)(q0 + row) * 1024 + l15 * 4) = ob;
  }
}

// ---------------------------------------------------------------- launch
extern "C" void kernel_launch(void* const* d_in, const int* in_sizes, int n_in,
                              void* d_out, int out_size, void* d_ws, size_t ws_size,
                              hipStream_t stream) {
  const float* hs = (const float*)d_in[1];
  const float* wq = (const float*)d_in[2];
  const float* wk = (const float*)d_in[3];
  const float* wv = (const float*)d_in[4];
  const float* wo = (const float*)d_in[5];

  char* ws = (char*)d_ws;
  const size_t MB = 1024 * 1024;
  bf16_t* WtQKV = (bf16_t*)(ws + 0 * MB);
  bf16_t* WtO = (bf16_t*)(ws + 6 * MB);
  bf16_t* hsb = (bf16_t*)(ws + 8 * MB);
  bf16_t* VT = (bf16_t*)(ws + 8 * MB);
  bf16_t* Qw = (bf16_t*)(ws + 24 * MB);
  bf16_t* Kw = (bf16_t*)(ws + 40 * MB);
  bf16_t* Vw = (bf16_t*)(ws + 56 * MB);
  bf16_t* Ow = (bf16_t*)(ws + 56 * MB);

  wtrans4_kernel<<<dim3(32, 32, 4), dim3(32, 8), 0, stream>>>(wq, wk, wv, wo, WtQKV);
  cvt_kernel<<<8192, 256, 0, stream>>>(hs, hsb);

  gemm_kernel<bf16_t, true><<<dim3(64, 24), 256, 0, stream>>>(hsb, WtQKV, Qw, 0);

  vtrans_kernel<<<dim3(64, 32, 4), dim3(32, 8), 0, stream>>>(Vw, VT);

  attn_kernel<<<dim3(32, 64), 256, 0, stream>>>(Qw, Kw, VT, Ow);

  gemm_kernel<float, false><<<dim3(64, 8), 256, 0, stream>>>(Ow, WtO, (float*)d_out, 0);
}

// Round 7
// 364.937 us; speedup vs baseline: 2.5512x; 2.5512x over previous
//
#include <hip/hip_runtime.h>
#include <hip/hip_bf16.h>

// Chronos2Attention on MI355X (gfx950). Inputs f32, output f32.
// Internally bf16 MFMA with fp32 accumulation.
// B=4, S=2048, D=1024, H=16, Dh=64. RoPE theta=10000, no 1/sqrt(d) scale.
//
// R7 = R6 with the scratch-spill bug fixed: R6's epilogue indexed accO[s]
// with runtime s=(w+p)&3 -> compiler demoted the WHOLE accumulator array to
// scratch (VGPR_Count 68, WRITE_SIZE 2.2 GB, 705 us). Now the phase loop
// selects the accO block through a wave-uniform if-chain with compile-time
// indices only. Everything else identical to R6.
//
// Workspace (72 MB):
//   0..6MB WtQKV | 6..8MB WtO | 8..24MB hsb->VT | 24..40 Qw | 40..56 Kw
//   56..72MB Vw->Ow

typedef __bf16 bf16_t;
typedef __bf16 bf16x4 __attribute__((ext_vector_type(4)));
typedef __bf16 bf16x8 __attribute__((ext_vector_type(8)));
typedef float f32x4 __attribute__((ext_vector_type(4)));

#define MFMA16(a, b, c) __builtin_amdgcn_mfma_f32_16x16x32_bf16((a), (b), (c), 0, 0, 0)

#define GLOAD_LDS(gp, lp) \
  __builtin_amdgcn_global_load_lds( \
      (const __attribute__((address_space(1))) void*)(gp), \
      (__attribute__((address_space(3))) void*)(lp), 16, 0, 0)

// ---------------------------------------------------------------- hs f32->bf16
__global__ __launch_bounds__(256) void cvt_kernel(const float* __restrict__ X,
                                                  bf16_t* __restrict__ Y) {
  const int i = (blockIdx.x * 256 + threadIdx.x) * 4;
  const f32x4 x = *(const f32x4*)(X + i);
  bf16x4 y;
#pragma unroll
  for (int k = 0; k < 4; k++) y[k] = (bf16_t)x[k];
  *(bf16x4*)(Y + i) = y;
}

// ---------------------------------------------------------------- weight transpose
__global__ __launch_bounds__(256) void wtrans4_kernel(
    const float* __restrict__ w0, const float* __restrict__ w1,
    const float* __restrict__ w2, const float* __restrict__ w3,
    bf16_t* __restrict__ out) {
  __shared__ bf16_t t[32][33];
  const int tx = threadIdx.x, ty = threadIdx.y;
  const int bx = blockIdx.x, by = blockIdx.y, z = blockIdx.z;
  const float* W = (z == 0) ? w0 : (z == 1) ? w1 : (z == 2) ? w2 : w3;
  bf16_t* Wt = out + (size_t)z * 1024 * 1024;
#pragma unroll
  for (int i = ty; i < 32; i += 8)
    t[i][tx] = (bf16_t)W[(size_t)(by * 32 + i) * 1024 + bx * 32 + tx];
  __syncthreads();
#pragma unroll
  for (int i = ty; i < 32; i += 8)
    Wt[(size_t)(bx * 32 + i) * 1024 + by * 32 + tx] = t[tx][i];
}

// ---------------------------------------------------------------- V transpose
// VT[b*1024 + c][s] = Vw[b*2048 + s][c].
__global__ __launch_bounds__(256) void vtrans_kernel(const bf16_t* __restrict__ V,
                                                     bf16_t* __restrict__ VT) {
  __shared__ bf16_t t[32][33];
  const int tx = threadIdx.x, ty = threadIdx.y;
  const int sx = blockIdx.x * 32, cy = blockIdx.y * 32, b = blockIdx.z;
  const bf16_t* Vb = V + (size_t)b * 2048 * 1024;
  bf16_t* VTb = VT + (size_t)b * 1024 * 2048;
#pragma unroll
  for (int i = ty; i < 32; i += 8)
    t[i][tx] = Vb[(size_t)(sx + i) * 1024 + cy + tx];
  __syncthreads();
#pragma unroll
  for (int i = ty; i < 32; i += 8)
    VTb[(size_t)(cy + i) * 2048 + sx + tx] = t[tx][i];
}

// ---------------------------------------------------------------- GEMM (+RoPE)
// Identical to R5 (proven): 128x128 tile, global_load_lds w=16, XOR swizzle.
template <typename TC, bool FUSED_QKV>
__global__ __launch_bounds__(256) void gemm_kernel(
    const bf16_t* __restrict__ A, const bf16_t* __restrict__ BtBase,
    TC* __restrict__ CBase, const int ropeIn) {
  constexpr int K = 1024, N = 1024;
  __shared__ __align__(16) bf16_t As[128 * 32];
  __shared__ __align__(16) bf16_t Bs[128 * 32];

  const int tid = threadIdx.x;
  const int lane = tid & 63, w = tid >> 6;
  const int l15 = lane & 15, quad = lane >> 4;
  const int wm = w >> 1, wn = w & 1;
  const int m0 = blockIdx.x * 128;

  int n0, rope;
  const bf16_t* Bt;
  TC* C;
  if (FUSED_QKV) {
    const int which = blockIdx.y >> 3;
    n0 = (blockIdx.y & 7) * 128;
    Bt = BtBase + (size_t)which * (1u << 20);
    C = CBase + (size_t)which * (8u << 20);
    rope = (which < 2);
  } else {
    n0 = blockIdx.y * 128;
    Bt = BtBase;
    C = CBase;
    rope = ropeIn;
  }

  f32x4 acc[4][4] = {};
  const int li8 = lane >> 3, j = lane & 7;

  for (int k0 = 0; k0 < K; k0 += 32) {
#pragma unroll
    for (int p = 0; p < 2; ++p) {
      const int g = w * 16 + p * 8 + li8;
      const int jp = j ^ (g & 7);
      const int row = 2 * g + (jp >> 2), kb = jp & 3;
      GLOAD_LDS(A + (size_t)(m0 + row) * K + k0 + kb * 8, As + (w * 16 + p * 8) * 64);
      GLOAD_LDS(Bt + (size_t)(n0 + row) * K + k0 + kb * 8, Bs + (w * 16 + p * 8) * 64);
    }
    __syncthreads();

    bf16x8 af[4], bfv[4];
#pragma unroll
    for (int mi = 0; mi < 4; mi++) {
      const int R = wm * 64 + mi * 16 + l15, g = R >> 1;
      const int jj = (((R & 1) << 2) | quad) ^ (g & 7);
      af[mi] = *(const bf16x8*)(As + g * 64 + jj * 8);
    }
#pragma unroll
    for (int ni = 0; ni < 4; ni++) {
      const int R = wn * 64 + ni * 16 + l15, g = R >> 1;
      const int jj = (((R & 1) << 2) | quad) ^ (g & 7);
      bfv[ni] = *(const bf16x8*)(Bs + g * 64 + jj * 8);
    }
#pragma unroll
    for (int mi = 0; mi < 4; mi++)
#pragma unroll
      for (int ni = 0; ni < 4; ni++)
        acc[mi][ni] = MFMA16(af[mi], bfv[ni], acc[mi][ni]);
    __syncthreads();
  }

#pragma unroll
  for (int mi = 0; mi < 4; mi++) {
    const int rbase = m0 + wm * 64 + mi * 16 + quad * 4;
    if (rope) {
#pragma unroll
      for (int r = 0; r < 4; r++) {
        const float pos = (float)((rbase + r) & 2047);
#pragma unroll
        for (int ni = 0; ni < 2; ni++) {
          const int d2 = ni * 16 + l15;
          const float invf = __powf(10000.0f, -(float)d2 * (1.0f / 32.0f));
          float sv, cv;
          __sincosf(pos * invf, &sv, &cv);
          const float a0 = acc[mi][ni][r], a2 = acc[mi][ni + 2][r];
          acc[mi][ni][r] = a0 * cv - a2 * sv;
          acc[mi][ni + 2][r] = a2 * cv + a0 * sv;
        }
      }
    }
#pragma unroll
    for (int ni = 0; ni < 4; ni++) {
      const int c0 = n0 + wn * 64 + ni * 16 + l15;
#pragma unroll
      for (int r = 0; r < 4; r++)
        C[(size_t)(rbase + r) * N + c0] = (TC)acc[mi][ni][r];
    }
  }
}

// ---------------------------------------------------------------- attention (R7)
// Block = 64 q rows of one (b,h), 4 waves, KV tile 128, wave w owns kv
// slice w*32..+31 for ALL 64 q. Q held in regs (8 A-frags). Per wave per
// tile: QK = 16 MFMAs (4 K-frag b128 reads), exp -> per-wave P[64][32] in
// LDS, PV = 16 MFMAs k=32 (4 P-rd + 4 V-rd b128) into partial O[64][64].
// End: phased cross-wave O + lsum reduction in LDS (arena reuse).
// NOTE: accO must only ever be indexed with compile-time constants --
// dynamic indexing demotes it to scratch (R6: 2.2 GB HBM writes, 5x slower).
#define PLSTR 40  // 32 kv + 8 pad (80 B rows: 16B-aligned for b128 reads)

__global__ __launch_bounds__(256, 2) void attn_kernel(const bf16_t* __restrict__ Q,
                                                      const bf16_t* __restrict__ K,
                                                      const bf16_t* __restrict__ VT,
                                                      bf16_t* __restrict__ O) {
  __shared__ __align__(16) char arena[53248];
  bf16_t* Kl = (bf16_t*)arena;             // [kv 128][d 64], XOR-swizzled, 16 KB
  bf16_t* Vl = (bf16_t*)(arena + 16384);   // [g=d*2+h][64], XOR-swizzled, 16 KB
  bf16_t* Pl = (bf16_t*)(arena + 32768);   // per-wave [64 q][PLSTR], 20 KB
  float* Obuf = (float*)arena;             // [64][68] f32 (after loop), 17.4 KB
  float* lsumB = (float*)(arena + 32768);  // [4][64] (after loop, in Pl region)

  const int tid = threadIdx.x;
  const int lane = tid & 63, w = tid >> 6;
  const int l15 = lane & 15, quad = lane >> 4;
  const int li8 = lane >> 3, j = lane & 7;
  const int q0 = blockIdx.x * 64;
  const int bh = blockIdx.y, b = bh >> 4, h = bh & 15;

  const size_t base = (size_t)b * 2048 * 1024 + (size_t)h * 64;
  const bf16_t* Qb = Q + base;
  const bf16_t* Kb = K + base;
  const bf16_t* VTb = VT + (size_t)(b * 1024 + h * 64) * 2048;

  // Q A-frags: qf[mb][t]: A[m = q0+mb*16+l15][k = t*32+quad*8 ..+7]
  bf16x8 qf[4][2];
#pragma unroll
  for (int mb = 0; mb < 4; mb++)
#pragma unroll
    for (int t = 0; t < 2; t++)
      qf[mb][t] = *(const bf16x8*)(Qb + (size_t)(q0 + mb * 16 + l15) * 1024 + t * 32 + quad * 8);

  f32x4 accO[4][4] = {};          // partial O[q mb][d nb] over this wave's kv
  float lsum[4][4] = {};          // partial row sums [mb][r]
  bf16_t* Plw = Pl + w * (64 * PLSTR);

  for (int kv0 = 0; kv0 < 2048; kv0 += 128) {
    // stage K[128][64] and V^T[64][128]; group = 128B chunk-row; slot j
    // holds chunk j^(g&7) (2-way reads free, m136)
#pragma unroll
    for (int p = 0; p < 4; ++p) {
      const int g = w * 32 + p * 8 + li8;
      const int blk = j ^ (g & 7);
      GLOAD_LDS(Kb + (size_t)(kv0 + g) * 1024 + blk * 8, Kl + (w * 32 + p * 8) * 64);
      GLOAD_LDS(VTb + (size_t)(g >> 1) * 2048 + kv0 + (g & 1) * 64 + blk * 8,
                Vl + (w * 32 + p * 8) * 64);
    }
    __syncthreads();

    // S slice = Q K^T : wave w computes S[64 q][kv w*32 .. +31]
#pragma unroll
    for (int nb2 = 0; nb2 < 2; nb2++) {
      f32x4 sc[4] = {};
#pragma unroll
      for (int t = 0; t < 2; t++) {
        const int R = w * 32 + nb2 * 16 + l15;  // kv row (= group)
        const int jj = (t * 4 + quad) ^ (R & 7);
        const bf16x8 kf = *(const bf16x8*)(Kl + R * 64 + jj * 8);
#pragma unroll
        for (int mb = 0; mb < 4; mb++)
          sc[mb] = MFMA16(qf[mb][t], kf, sc[mb]);
      }
      // exp + partial sums + P store (C-layout -> slice-local [q][kv32])
#pragma unroll
      for (int mb = 0; mb < 4; mb++)
#pragma unroll
        for (int r = 0; r < 4; r++) {
          const float p = __expf(sc[mb][r]);
          lsum[mb][r] += p;
          Plw[(mb * 16 + quad * 4 + r) * PLSTR + nb2 * 16 + l15] = (bf16_t)p;
        }
    }
    __asm__ volatile("s_waitcnt lgkmcnt(0)" ::: "memory");  // per-wave Pl drain

    // O_partial += P V over kv slice (k=32 exactly)
    bf16x8 pf[4], vf[4];
#pragma unroll
    for (int mb = 0; mb < 4; mb++)
      pf[mb] = *(const bf16x8*)(Plw + (mb * 16 + l15) * PLSTR + quad * 8);
#pragma unroll
    for (int nb = 0; nb < 4; nb++) {
      const int R = nb * 16 + l15;                    // d row
      const int g = R * 2 + (w >> 1);                 // VT group: kv-half w>>1
      const int jj = ((w & 1) * 4 + quad) ^ (g & 7);  // chunk = kv-in-half/8
      vf[nb] = *(const bf16x8*)(Vl + g * 64 + jj * 8);
    }
#pragma unroll
    for (int mb = 0; mb < 4; mb++)
#pragma unroll
      for (int nb = 0; nb < 4; nb++)
        accO[mb][nb] = MFMA16(pf[mb], vf[nb], accO[mb][nb]);
    __syncthreads();  // Kl/Vl reuse next tile
  }

  // ---- cross-wave reduction (arena reused; all waves past final barrier) ----
#pragma unroll
  for (int mb = 0; mb < 4; mb++)
#pragma unroll
    for (int r = 0; r < 4; r++) {
      float s = lsum[mb][r];
      s += __shfl_xor(s, 1);
      s += __shfl_xor(s, 2);
      s += __shfl_xor(s, 4);
      s += __shfl_xor(s, 8);
      lsum[mb][r] = s;
    }
  if (l15 == 0) {
#pragma unroll
    for (int mb = 0; mb < 4; mb++)
#pragma unroll
      for (int r = 0; r < 4; r++)
        lsumB[w * 64 + mb * 16 + quad * 4 + r] = lsum[mb][r];
  }

  // Phased O accumulation into Obuf[64][68]. s=(w+p)&3 is wave-uniform; the
  // if-chain keeps accO indexing compile-time-constant (NO dynamic indexing).
#pragma unroll
  for (int p = 0; p < 4; p++) {
    const int s = (w + p) & 3;
    f32x4 v0, v1, v2, v3;
    if (s == 0)      { v0 = accO[0][0]; v1 = accO[0][1]; v2 = accO[0][2]; v3 = accO[0][3]; }
    else if (s == 1) { v0 = accO[1][0]; v1 = accO[1][1]; v2 = accO[1][2]; v3 = accO[1][3]; }
    else if (s == 2) { v0 = accO[2][0]; v1 = accO[2][1]; v2 = accO[2][2]; v3 = accO[2][3]; }
    else             { v0 = accO[3][0]; v1 = accO[3][1]; v2 = accO[3][2]; v3 = accO[3][3]; }
    float* Orow = Obuf + (s * 16 + quad * 4) * 68 + l15;
    if (p == 0) {
#pragma unroll
      for (int r = 0; r < 4; r++) {
        Orow[r * 68 + 0]  = v0[r];
        Orow[r * 68 + 16] = v1[r];
        Orow[r * 68 + 32] = v2[r];
        Orow[r * 68 + 48] = v3[r];
      }
    } else {
#pragma unroll
      for (int r = 0; r < 4; r++) {
        Orow[r * 68 + 0]  += v0[r];
        Orow[r * 68 + 16] += v1[r];
        Orow[r * 68 + 32] += v2[r];
        Orow[r * 68 + 48] += v3[r];
      }
    }
    __syncthreads();
  }

  // final: wave w stores q rows w*16..+15, coalesced bf16x4
  bf16_t* Ob = O + base;
#pragma unroll
  for (int rr = 0; rr < 4; rr++) {
    const int row = w * 16 + rr * 4 + quad;
    const f32x4 o = *(const f32x4*)(Obuf + row * 68 + l15 * 4);
    const float inv =
        1.0f / (lsumB[row] + lsumB[64 + row] + lsumB[128 + row] + lsumB[192 + row]);
    bf16x4 ob;
#pragma unroll
    for (int c = 0; c < 4; c++) ob[c] = (bf16_t)(o[c] * inv);
    *(bf16x4*)(Ob + (size_t)(q0 + row) * 1024 + l15 * 4) = ob;
  }
}

// ---------------------------------------------------------------- launch
extern "C" void kernel_launch(void* const* d_in, const int* in_sizes, int n_in,
                              void* d_out, int out_size, void* d_ws, size_t ws_size,
                              hipStream_t stream) {
  const float* hs = (const float*)d_in[1];
  const float* wq = (const float*)d_in[2];
  const float* wk = (const float*)d_in[3];
  const float* wv = (const float*)d_in[4];
  const float* wo = (const float*)d_in[5];

  char* ws = (char*)d_ws;
  const size_t MB = 1024 * 1024;
  bf16_t* WtQKV = (bf16_t*)(ws + 0 * MB);
  bf16_t* WtO = (bf16_t*)(ws + 6 * MB);
  bf16_t* hsb = (bf16_t*)(ws + 8 * MB);
  bf16_t* VT = (bf16_t*)(ws + 8 * MB);
  bf16_t* Qw = (bf16_t*)(ws + 24 * MB);
  bf16_t* Kw = (bf16_t*)(ws + 40 * MB);
  bf16_t* Vw = (bf16_t*)(ws + 56 * MB);
  bf16_t* Ow = (bf16_t*)(ws + 56 * MB);

  wtrans4_kernel<<<dim3(32, 32, 4), dim3(32, 8), 0, stream>>>(wq, wk, wv, wo, WtQKV);
  cvt_kernel<<<8192, 256, 0, stream>>>(hs, hsb);

  gemm_kernel<bf16_t, true><<<dim3(64, 24), 256, 0, stream>>>(hsb, WtQKV, Qw, 0);

  vtrans_kernel<<<dim3(64, 32, 4), dim3(32, 8), 0, stream>>>(Vw, VT);

  attn_kernel<<<dim3(32, 64), 256, 0, stream>>>(Qw, Kw, VT, Ow);

  gemm_kernel<float, false><<<dim3(64, 8), 256, 0, stream>>>(Ow, WtO, (float*)d_out, 0);
}